// Round 5
// baseline (572.712 us; speedup 1.0000x reference)
//
#include <hip/hip_runtime.h>

// ---------------------------------------------------------------------------
// RGAT 2-hop, N=100000, E=1600000, D=64, R=64.
// R5 = R4 + (a) bf16 for all randomly-gathered data (tail emb rows, TV
// table, GEMM A-read): halves random-fill bytes, working set 25.6->12.8 MB
// fits per-XCD L2 much better. (b) CSR cursor colocated in csr[] at each
// row base: fill's atomic + entry store hit the same line; rowstart becomes
// a read-only L2-cacheable array. Logits via HU[n][r]=emb.u_r (fp32,
// coalesced) + TV[t][r] (bf16, gathered); plain exp (|e| small).
// ---------------------------------------------------------------------------

#define NEG_SLOPE 0.2f

__device__ __forceinline__ float b2f(unsigned short u) {
    return __uint_as_float(((unsigned)u) << 16);
}
__device__ __forceinline__ unsigned short f2b(float x) {  // RNE
    unsigned u = __float_as_uint(x);
    unsigned r = u + 0x7fffu + ((u >> 16) & 1u);
    return (unsigned short)(r >> 16);
}

// Wuv[r*128 + i] = sum_j W[i][j] * rel[r][j],  i in [0,128)
__global__ void proj_kernel(const float* __restrict__ W,
                            const float* __restrict__ rel,
                            float* __restrict__ Wuv) {
    int r = blockIdx.x;
    int i = threadIdx.x;  // 0..127
    __shared__ float rels[64];
    if (i < 64) rels[i] = rel[r * 64 + i];
    __syncthreads();
    float s = 0.f;
#pragma unroll
    for (int j = 0; j < 64; ++j) s += W[i * 64 + j] * rels[j];
    Wuv[r * 128 + i] = s;
}

// fp32 -> bf16 cast (float4 -> ushort4), n4 = total/4
__global__ __launch_bounds__(256) void cast_kernel(
    const float* __restrict__ src, unsigned short* __restrict__ dst, int n4) {
    int i = blockIdx.x * 256 + threadIdx.x;
    if (i >= n4) return;
    float4 v = *(const float4*)(src + (long)i * 4);
    ushort4 o = {f2b(v.x), f2b(v.y), f2b(v.z), f2b(v.w)};
    *(ushort4*)(dst + (long)i * 4) = o;
}

// ---------------- CSR build ----------------

__global__ __launch_bounds__(256) void hist_kernel(
    const int* __restrict__ head, int* __restrict__ deg, int E) {
    int i = blockIdx.x * 256 + threadIdx.x;
    if (i < E) atomicAdd(deg + head[i], 1);
}

__global__ __launch_bounds__(256) void block_sum_kernel(
    const int* __restrict__ deg, int* __restrict__ bsum, int N) {
    int i = blockIdx.x * 256 + threadIdx.x;
    int v = (i < N) ? deg[i] : 0;
#pragma unroll
    for (int m = 1; m < 64; m <<= 1) v += __shfl_xor(v, m);
    __shared__ int ws[4];
    if ((threadIdx.x & 63) == 0) ws[threadIdx.x >> 6] = v;
    __syncthreads();
    if (threadIdx.x == 0) bsum[blockIdx.x] = ws[0] + ws[1] + ws[2] + ws[3];
}

// single-block Hillis-Steele exclusive scan of bsum (nb <= 512)
__global__ __launch_bounds__(512) void scan_bsum_kernel(int* bsum, int nb) {
    __shared__ int s[512];
    int i = threadIdx.x;
    s[i] = (i < nb) ? bsum[i] : 0;
    __syncthreads();
    for (int off = 1; off < 512; off <<= 1) {
        int v = (i >= off) ? s[i - off] : 0;
        __syncthreads();
        s[i] += v;
        __syncthreads();
    }
    if (i < nb) bsum[i] = (i == 0) ? 0 : s[i - 1];
}

// rowstart (exclusive scan of deg) + zero the per-row counter slot in csr.
// csr layout: row i occupies csr[rowstart[i]+i .. rowstart[i+1]+i]:
// slot 0 = running counter, then deg[i] packed entries.
__global__ __launch_bounds__(256) void row_start_kernel(
    const int* __restrict__ deg, const int* __restrict__ bsum,
    int* __restrict__ rowstart, int* __restrict__ csr, int N, int E) {
    int i = blockIdx.x * 256 + threadIdx.x;
    int v = (i < N) ? deg[i] : 0;
    int lane = threadIdx.x & 63;
    int wid = threadIdx.x >> 6;
    int sc = v;  // wave inclusive scan
#pragma unroll
    for (int off = 1; off < 64; off <<= 1) {
        int t = __shfl_up(sc, off);
        if (lane >= off) sc += t;
    }
    __shared__ int wsum[4];
    if (lane == 63) wsum[wid] = sc;
    __syncthreads();
    int wo = 0;
    for (int w = 0; w < wid; ++w) wo += wsum[w];
    int ex = sc - v + wo + bsum[blockIdx.x];
    if (i < N) {
        rowstart[i] = ex;
        csr[ex + i] = 0;  // zero counter slot (sequential-ish addresses)
    }
    if (i == N - 1) rowstart[N] = E;
}

__global__ __launch_bounds__(256) void fill_kernel(
    const int* __restrict__ head, const int* __restrict__ tail,
    const int* __restrict__ etype, const int* __restrict__ rowstart,
    int* __restrict__ csr, int E) {
    int i = blockIdx.x * 256 + threadIdx.x;
    if (i >= E) return;
    int h = head[i];
    long rb = (long)rowstart[h] + h;       // counter slot (rowstart: RO, L2-cached)
    int c = atomicAdd(csr + rb, 1);        // same line as entries for deg<31
    csr[rb + 1 + c] = (tail[i] << 6) | etype[i];   // t < 2^17, r < 64
}

// ---------------- HU/TV GEMM ----------------
// A read as bf16. HU[n][r] (fp32, coalesced later) ; TV[n][r] -> bf16 table.
// Block = 256 thr computes 64-node x 128-col tile; thread = 4x8 micro-tile.
__global__ __launch_bounds__(256) void hu_tv_gemm(
    const unsigned short* __restrict__ embb, const float* __restrict__ Wuv,
    float* __restrict__ HU, unsigned short* __restrict__ TVb, int N) {
    __shared__ float sA[64 * 68];   // sA[d*68+n] = emb[nbase+n][d] (transposed)
    __shared__ float sB[64 * 132];  // sB[d*132+c]: c<64 -> U_c[d], c>=64 -> V_{c-64}[d]
    int tid = threadIdx.x;
    long nbase = (long)blockIdx.x * 64;

    for (int i = tid; i < 64 * 128; i += 256) {
        int r = i >> 7, k = i & 127;
        float v = Wuv[i];
        int d = (k < 64) ? k : (k - 64);
        int c = (k < 64) ? r : (64 + r);
        sB[d * 132 + c] = v;
    }
    for (int i = tid; i < 64 * 16; i += 256) {
        int n = i >> 4, q = i & 15;
        long node = nbase + n;
        ushort4 u = (node < N) ? *(const ushort4*)(embb + node * 64 + q * 4)
                               : make_ushort4(0, 0, 0, 0);
        sA[(q * 4 + 0) * 68 + n] = b2f(u.x);
        sA[(q * 4 + 1) * 68 + n] = b2f(u.y);
        sA[(q * 4 + 2) * 68 + n] = b2f(u.z);
        sA[(q * 4 + 3) * 68 + n] = b2f(u.w);
    }
    __syncthreads();

    int wv = tid >> 6, lane = tid & 63;
    int g = lane & 15, cg = lane >> 4;
    int c0 = wv * 32 + cg * 8;       // wave cols are 32-aligned: all-HU or all-TV
    float acc[4][8] = {};
#pragma unroll 8
    for (int d = 0; d < 64; ++d) {
        const float4 a  = *(const float4*)&sA[d * 68 + g * 4];
        const float4 b0 = *(const float4*)&sB[d * 132 + c0];
        const float4 b1 = *(const float4*)&sB[d * 132 + c0 + 4];
        float av[4] = {a.x, a.y, a.z, a.w};
        float bv[8] = {b0.x, b0.y, b0.z, b0.w, b1.x, b1.y, b1.z, b1.w};
#pragma unroll
        for (int j = 0; j < 4; ++j)
#pragma unroll
            for (int c = 0; c < 8; ++c) acc[j][c] += av[j] * bv[c];
    }
    int cc = c0 & 63;
    if (c0 < 64) {  // HU fp32
#pragma unroll
        for (int j = 0; j < 4; ++j) {
            long node = nbase + g * 4 + j;
            if (node < N) {
                float4 o0 = {acc[j][0], acc[j][1], acc[j][2], acc[j][3]};
                float4 o1 = {acc[j][4], acc[j][5], acc[j][6], acc[j][7]};
                *(float4*)(HU + node * 64 + cc) = o0;
                *(float4*)(HU + node * 64 + cc + 4) = o1;
            }
        }
    } else {        // TV bf16
#pragma unroll
        for (int j = 0; j < 4; ++j) {
            long node = nbase + g * 4 + j;
            if (node < N) {
                ushort4 o0 = {f2b(acc[j][0]), f2b(acc[j][1]), f2b(acc[j][2]), f2b(acc[j][3])};
                ushort4 o1 = {f2b(acc[j][4]), f2b(acc[j][5]), f2b(acc[j][6]), f2b(acc[j][7])};
                *(ushort4*)(TVb + node * 64 + cc) = o0;
                *(ushort4*)(TVb + node * 64 + cc + 4) = o1;
            }
        }
    }
}

// ---------------- fused hop ----------------
// One wave per node, lane = dim. Phase A: 64 edge weights in parallel
// (lane = edge), all shuffles exec-unconditional. Phase B: weighted bf16
// row gather, unrolled. hd/gathers from bf16; residual math in fp32.
__global__ __launch_bounds__(256) void hop_kernel(
    const int* __restrict__ rowstart, const int* __restrict__ csr,
    const float* __restrict__ HU, const unsigned short* __restrict__ TVb,
    const unsigned short* __restrict__ embb, const float* res_prev,
    unsigned short* embb_out, float* res_out, int N) {
    int node = blockIdx.x * 4 + (threadIdx.x >> 6);
    int lane = threadIdx.x & 63;
    if (node >= N) return;
    long base = (long)node * 64 + lane;
    float hd = b2f(embb[base]);
    float hu = HU[base];                 // lane d holds HU[node][d]
    int r0 = rowstart[node], r1 = rowstart[node + 1];
    int deg = r1 - r0;
    long ebase = (long)r0 + node + 1;    // skip counter slot
    float agg = 0.f, lsum = 0.f;

    for (int s = 0; s < deg; s += 64) {
        int cnt = min(64, deg - s);
        int pe = (lane < cnt) ? csr[ebase + s + lane] : 0;
        int t = pe >> 6, r = pe & 63;
        // all lanes active at shuffles; pad lanes use t=0,r=0, weight 0.
        float hur = __shfl(hu, r);
        float tv = b2f(TVb[(long)t * 64 + r]);
        float p = hur + tv;
        p = p > 0.f ? p : NEG_SLOPE * p;
        float w = (lane < cnt) ? __expf(p) : 0.f;
        lsum += w;
#pragma unroll 8
        for (int i = 0; i < cnt; ++i) {
            float wi = __shfl(w, i);
            int ti = __shfl(t, i);
            agg += wi * b2f(embb[(long)ti * 64 + lane]);
        }
    }
    float l = lsum;
    l += __shfl_xor(l, 1);  l += __shfl_xor(l, 2);  l += __shfl_xor(l, 4);
    l += __shfl_xor(l, 8);  l += __shfl_xor(l, 16); l += __shfl_xor(l, 32);
    float val = hd;
    if (l > 0.f) val += agg / l;
    float sq = val * val;
    sq += __shfl_xor(sq, 1);  sq += __shfl_xor(sq, 2);  sq += __shfl_xor(sq, 4);
    sq += __shfl_xor(sq, 8);  sq += __shfl_xor(sq, 16); sq += __shfl_xor(sq, 32);
    float nv = val / fmaxf(sqrtf(sq), 1e-12f);
    if (embb_out) embb_out[base] = f2b(nv);
    res_out[base] = 0.5f * res_prev[base] + nv;
}

extern "C" void kernel_launch(void* const* d_in, const int* in_sizes, int n_in,
                              void* d_out, int out_size, void* d_ws, size_t ws_size,
                              hipStream_t stream) {
    const int*   edge_index = (const int*)d_in[0];   // [2, E]
    const int*   etype      = (const int*)d_in[1];   // [E]
    const float* ent        = (const float*)d_in[2]; // [N, 64]
    const float* rel        = (const float*)d_in[3]; // [R, 64]
    const float* W          = (const float*)d_in[4]; // [128, 64]

    const int E = in_sizes[1];
    const int N = in_sizes[2] / 64;
    const int R = in_sizes[3] / 64;
    const int* head = edge_index;
    const int* tail = edge_index + E;
    float* out = (float*)d_out;

    // workspace layout
    char* w = (char*)d_ws;
    float* Wuv = (float*)w;            w += (size_t)R * 128 * 4;
    int* deg = (int*)w;                w += ((size_t)N + 8) * 4;
    int* rowstart = (int*)w;           w += ((size_t)N + 8) * 4;
    int* bsum = (int*)w;               w += 512 * 4;
    int* csr = (int*)w;                w += ((size_t)E + N + 8) * 4;
    float* HU = (float*)w;             w += (size_t)N * 64 * 4;
    unsigned short* TVb = (unsigned short*)w;   w += (size_t)N * 64 * 2;
    unsigned short* entb = (unsigned short*)w;  w += (size_t)N * 64 * 2;
    unsigned short* emb1b = (unsigned short*)w; w += (size_t)N * 64 * 2;

    const int nb = (N + 255) / 256;
    const int eb = (E + 255) / 256;
    const int hb = (N + 3) / 4;
    const int gb = (N + 63) / 64;
    const int cb = (N * 16 + 255) / 256;  // cast: N*64/4 float4s

    proj_kernel<<<R, 128, 0, stream>>>(W, rel, Wuv);
    cast_kernel<<<cb, 256, 0, stream>>>(ent, entb, N * 16);

    // CSR build (graph constant across hops)
    hipMemsetAsync(deg, 0, (size_t)N * 4, stream);
    hist_kernel<<<eb, 256, 0, stream>>>(head, deg, E);
    block_sum_kernel<<<nb, 256, 0, stream>>>(deg, bsum, N);
    scan_bsum_kernel<<<1, 512, 0, stream>>>(bsum, nb);
    row_start_kernel<<<nb, 256, 0, stream>>>(deg, bsum, rowstart, csr, N, E);
    fill_kernel<<<eb, 256, 0, stream>>>(head, tail, etype, rowstart, csr, E);

    // hop 1
    hu_tv_gemm<<<gb, 256, 0, stream>>>(entb, Wuv, HU, TVb, N);
    hop_kernel<<<hb, 256, 0, stream>>>(rowstart, csr, HU, TVb, entb, ent, emb1b, out, N);
    // hop 2 (res in place)
    hu_tv_gemm<<<gb, 256, 0, stream>>>(emb1b, Wuv, HU, TVb, N);
    hop_kernel<<<hb, 256, 0, stream>>>(rowstart, csr, HU, TVb, emb1b, out, nullptr, out, N);
}